// Round 2
// baseline (571.210 us; speedup 1.0000x reference)
//
#include <hip/hip_runtime.h>

#define N_SRC 100000
#define N_DST 20000
#define NE 640000
#define IN_F 256
#define NH 4
#define DF 32
#define NCOL 128  /* NH*DF */

// ---------------- K0: fold attn vectors into W (fp64) ----------------
// Wlr[k][j] = sum_d W[k][ (j&3)*32+d ] * attn_{l if j<4 else r}[(j&3)*32+d]
__global__ void k_prep(const float* __restrict__ W,
                       const float* __restrict__ attn_l,
                       const float* __restrict__ attn_r,
                       double* __restrict__ Wlr) {
    int k = threadIdx.x;  // 256 threads, one per k
    for (int j = 0; j < 8; ++j) {
        const float* attn = (j < 4) ? attn_l : attn_r;
        int hh = j & 3;
        double s = 0.0;
        for (int d = 0; d < DF; ++d)
            s += (double)W[k * NCOL + hh * DF + d] * (double)attn[hh * DF + d];
        Wlr[k * 8 + j] = s;
    }
}

// ---------------- K1: h = x @ W (fp32) ----------------
__global__ __launch_bounds__(256) void k_gemm(const float* __restrict__ x,
                                              const float* __restrict__ W,
                                              float* __restrict__ h) {
    __shared__ float xs[64][IN_F];
    const int row0 = blockIdx.x * 64;
    const int tid = threadIdx.x;

    for (int i = tid; i < 64 * (IN_F / 4); i += 256) {
        int r = i / (IN_F / 4);
        int kc = i % (IN_F / 4);
        float4 v = make_float4(0.f, 0.f, 0.f, 0.f);
        if (row0 + r < N_SRC)
            v = ((const float4*)(x + (size_t)(row0 + r) * IN_F))[kc];
        ((float4*)&xs[r][0])[kc] = v;
    }
    __syncthreads();

    const int c0 = (tid & 31) * 4;
    const int r0 = (tid >> 5) * 8;

    float4 acc[8];
#pragma unroll
    for (int j = 0; j < 8; ++j) acc[j] = make_float4(0.f, 0.f, 0.f, 0.f);

    for (int k = 0; k < IN_F; k += 4) {
        float4 w0 = *((const float4*)(W + (size_t)(k + 0) * NCOL + c0));
        float4 w1 = *((const float4*)(W + (size_t)(k + 1) * NCOL + c0));
        float4 w2 = *((const float4*)(W + (size_t)(k + 2) * NCOL + c0));
        float4 w3 = *((const float4*)(W + (size_t)(k + 3) * NCOL + c0));
#pragma unroll
        for (int j = 0; j < 8; ++j) {
            float4 xv = *((const float4*)&xs[r0 + j][k]);
            acc[j].x += xv.x * w0.x + xv.y * w1.x + xv.z * w2.x + xv.w * w3.x;
            acc[j].y += xv.x * w0.y + xv.y * w1.y + xv.z * w2.y + xv.w * w3.y;
            acc[j].z += xv.x * w0.z + xv.y * w1.z + xv.z * w2.z + xv.w * w3.z;
            acc[j].w += xv.x * w0.w + xv.y * w1.w + xv.z * w2.w + xv.w * w3.w;
        }
    }

#pragma unroll
    for (int j = 0; j < 8; ++j) {
        int row = row0 + r0 + j;
        if (row < N_SRC)
            *((float4*)(h + (size_t)row * NCOL + c0)) = acc[j];
    }
}

// ---------------- K2: el / er_src via fp64 dot(x_row, Wlr) ----------------
// one wave per row per iteration; lane l covers k = 4l..4l+3
__global__ __launch_bounds__(256) void k_scores(const float* __restrict__ x,
                                                const double* __restrict__ Wlr,
                                                double* __restrict__ el,
                                                double* __restrict__ er_src) {
    const int lane = threadIdx.x & 63;
    const int wid = (blockIdx.x * 256 + threadIdx.x) >> 6;  // global wave id
    const int nwaves = gridDim.x * 4;

    // per-lane slice of Wlr (stays in registers / L1)
    double wreg[4][8];
#pragma unroll
    for (int i = 0; i < 4; ++i)
#pragma unroll
        for (int j = 0; j < 8; ++j)
            wreg[i][j] = Wlr[(lane * 4 + i) * 8 + j];

    for (int row = wid; row < N_SRC; row += nwaves) {
        float4 xv = *((const float4*)(x + (size_t)row * IN_F + lane * 4));
        double acc[8];
#pragma unroll
        for (int j = 0; j < 8; ++j) acc[j] = 0.0;
        const double xd[4] = {(double)xv.x, (double)xv.y, (double)xv.z, (double)xv.w};
#pragma unroll
        for (int i = 0; i < 4; ++i)
#pragma unroll
            for (int j = 0; j < 8; ++j)
                acc[j] += xd[i] * wreg[i][j];
        // wave-wide butterfly reduction (fp64)
#pragma unroll
        for (int j = 0; j < 8; ++j) {
#pragma unroll
            for (int m = 32; m >= 1; m >>= 1)
                acc[j] += __shfl_xor(acc[j], m);
        }
        if (lane == 0) {
#pragma unroll
            for (int hh = 0; hh < 4; ++hh) {
                el[(size_t)row * NH + hh] = acc[hh];
                er_src[(size_t)row * NH + hh] = acc[4 + hh];
            }
        }
    }
}

// ---------------- K3: gather er for dst nodes ----------------
__global__ __launch_bounds__(256) void k_gather(const int* __restrict__ dst_to_src,
                                                const double* __restrict__ er_src,
                                                double* __restrict__ er_dst) {
    int gid = blockIdx.x * 256 + threadIdx.x;
    if (gid >= N_DST * NH) return;
    int nd = gid >> 2, hh = gid & 3;
    er_dst[gid] = er_src[(size_t)dst_to_src[nd] * NH + hh];
}

// ---------------- K4: segment-sum of leaky(e) in fp64 ----------------
__global__ __launch_bounds__(256) void k_edge_sum(const int* __restrict__ src_idx,
                                                  const int* __restrict__ dst_idx,
                                                  const double* __restrict__ el,
                                                  const double* __restrict__ er_dst,
                                                  double* __restrict__ S) {
    int gid = blockIdx.x * 256 + threadIdx.x;
    if (gid >= NE * NH) return;
    int eid = gid >> 2, hh = gid & 3;
    int s = src_idx[eid], d = dst_idx[eid];
    double e = el[(size_t)s * NH + hh] + er_dst[(size_t)d * NH + hh];
    e = (e >= 0.0) ? e : 0.2 * e;
    atomicAdd(S + (size_t)d * NH + hh, e);
}

// ---------------- K4b: attention = e / S (fp64 -> fp32) ----------------
__global__ __launch_bounds__(256) void k_att(const int* __restrict__ src_idx,
                                             const int* __restrict__ dst_idx,
                                             const double* __restrict__ el,
                                             const double* __restrict__ er_dst,
                                             const double* __restrict__ S,
                                             float* __restrict__ att) {
    int gid = blockIdx.x * 256 + threadIdx.x;
    if (gid >= NE * NH) return;
    int eid = gid >> 2, hh = gid & 3;
    int s = src_idx[eid], d = dst_idx[eid];
    double e = el[(size_t)s * NH + hh] + er_dst[(size_t)d * NH + hh];
    e = (e >= 0.0) ? e : 0.2 * e;
    att[gid] = (float)(e / S[(size_t)d * NH + hh]);
}

// ---------------- K5: weighted scatter-add (fp32) ----------------
__global__ __launch_bounds__(256) void k_scatter(const int* __restrict__ src_idx,
                                                 const int* __restrict__ dst_idx,
                                                 const float* __restrict__ att,
                                                 const float* __restrict__ h,
                                                 float* __restrict__ out) {
    int gid = blockIdx.x * 256 + threadIdx.x;  // NE*128 = 81.92M
    int eid = gid >> 7, c = gid & 127;
    int s = src_idx[eid], d = dst_idx[eid];
    float a = att[eid * NH + (c >> 5)];
    float val = a * h[(size_t)s * NCOL + c];
    atomicAdd(out + (size_t)d * NCOL + c, val);
}

extern "C" void kernel_launch(void* const* d_in, const int* in_sizes, int n_in,
                              void* d_out, int out_size, void* d_ws, size_t ws_size,
                              hipStream_t stream) {
    const float* x      = (const float*)d_in[0];
    const float* W      = (const float*)d_in[1];
    const float* attn_l = (const float*)d_in[2];
    const float* attn_r = (const float*)d_in[3];
    const int* src_idx  = (const int*)d_in[4];
    const int* dst_idx  = (const int*)d_in[5];
    const int* dst_to_src = (const int*)d_in[6];
    float* out = (float*)d_out;

    // workspace layout: fp64 chunk first (8B aligned), then fp32
    char* p = (char*)d_ws;
    double* Wlr    = (double*)p;  p += (size_t)IN_F * 8 * sizeof(double);      // 16 KB
    double* el     = (double*)p;  p += (size_t)N_SRC * NH * sizeof(double);    // 3.2 MB
    double* er_src = (double*)p;  p += (size_t)N_SRC * NH * sizeof(double);    // 3.2 MB
    double* er_dst = (double*)p;  p += (size_t)N_DST * NH * sizeof(double);    // 0.64 MB
    double* S      = (double*)p;  p += (size_t)N_DST * NH * sizeof(double);    // 0.64 MB
    float*  h      = (float*)p;   p += (size_t)N_SRC * NCOL * sizeof(float);   // 51.2 MB
    float*  att    = (float*)p;   p += (size_t)NE * NH * sizeof(float);        // 10.24 MB

    hipMemsetAsync(out, 0, (size_t)out_size * sizeof(float), stream);
    hipMemsetAsync(S, 0, (size_t)N_DST * NH * sizeof(double), stream);

    k_prep<<<1, IN_F, 0, stream>>>(W, attn_l, attn_r, Wlr);
    k_gemm<<<(N_SRC + 63) / 64, 256, 0, stream>>>(x, W, h);
    k_scores<<<512, 256, 0, stream>>>(x, Wlr, el, er_src);
    k_gather<<<(N_DST * NH + 255) / 256, 256, 0, stream>>>(dst_to_src, er_src, er_dst);
    k_edge_sum<<<(NE * NH + 255) / 256, 256, 0, stream>>>(src_idx, dst_idx, el, er_dst, S);
    k_att<<<(NE * NH + 255) / 256, 256, 0, stream>>>(src_idx, dst_idx, el, er_dst, S, att);
    k_scatter<<<((size_t)NE * NCOL) / 256, 256, 0, stream>>>(src_idx, dst_idx, att, h, out);
}

// Round 3
// 436.488 us; speedup vs baseline: 1.3087x; 1.3087x over previous
//
#include <hip/hip_runtime.h>

#define N_SRC 100000
#define N_DST 20000
#define NE 640000
#define IN_F 256
#define NH 4
#define DF 32
#define NCOL 128  /* NH*DF */

// ---------------- K0: fold attn vectors into W (fp64) ----------------
__global__ void k_prep(const float* __restrict__ W,
                       const float* __restrict__ attn_l,
                       const float* __restrict__ attn_r,
                       double* __restrict__ Wlr) {
    int k = threadIdx.x;  // 256 threads, one per k
    for (int j = 0; j < 8; ++j) {
        const float* attn = (j < 4) ? attn_l : attn_r;
        int hh = j & 3;
        double s = 0.0;
        for (int d = 0; d < DF; ++d)
            s += (double)W[k * NCOL + hh * DF + d] * (double)attn[hh * DF + d];
        Wlr[k * 8 + j] = s;
    }
}

// ---------------- K1: h = x @ W (fp32) ----------------
__global__ __launch_bounds__(256) void k_gemm(const float* __restrict__ x,
                                              const float* __restrict__ W,
                                              float* __restrict__ h) {
    __shared__ float xs[64][IN_F];
    const int row0 = blockIdx.x * 64;
    const int tid = threadIdx.x;

    for (int i = tid; i < 64 * (IN_F / 4); i += 256) {
        int r = i / (IN_F / 4);
        int kc = i % (IN_F / 4);
        float4 v = make_float4(0.f, 0.f, 0.f, 0.f);
        if (row0 + r < N_SRC)
            v = ((const float4*)(x + (size_t)(row0 + r) * IN_F))[kc];
        ((float4*)&xs[r][0])[kc] = v;
    }
    __syncthreads();

    const int c0 = (tid & 31) * 4;
    const int r0 = (tid >> 5) * 8;

    float4 acc[8];
#pragma unroll
    for (int j = 0; j < 8; ++j) acc[j] = make_float4(0.f, 0.f, 0.f, 0.f);

    for (int k = 0; k < IN_F; k += 4) {
        float4 w0 = *((const float4*)(W + (size_t)(k + 0) * NCOL + c0));
        float4 w1 = *((const float4*)(W + (size_t)(k + 1) * NCOL + c0));
        float4 w2 = *((const float4*)(W + (size_t)(k + 2) * NCOL + c0));
        float4 w3 = *((const float4*)(W + (size_t)(k + 3) * NCOL + c0));
#pragma unroll
        for (int j = 0; j < 8; ++j) {
            float4 xv = *((const float4*)&xs[r0 + j][k]);
            acc[j].x += xv.x * w0.x + xv.y * w1.x + xv.z * w2.x + xv.w * w3.x;
            acc[j].y += xv.x * w0.y + xv.y * w1.y + xv.z * w2.y + xv.w * w3.y;
            acc[j].z += xv.x * w0.z + xv.y * w1.z + xv.z * w2.z + xv.w * w3.z;
            acc[j].w += xv.x * w0.w + xv.y * w1.w + xv.z * w2.w + xv.w * w3.w;
        }
    }

#pragma unroll
    for (int j = 0; j < 8; ++j) {
        int row = row0 + r0 + j;
        if (row < N_SRC)
            *((float4*)(h + (size_t)row * NCOL + c0)) = acc[j];
    }
}

// ---------------- K2: el / er_src via fp64 dot(x_row, Wlr) ----------------
__global__ __launch_bounds__(256) void k_scores(const float* __restrict__ x,
                                                const double* __restrict__ Wlr,
                                                double* __restrict__ el,
                                                double* __restrict__ er_src) {
    const int lane = threadIdx.x & 63;
    const int wid = (blockIdx.x * 256 + threadIdx.x) >> 6;
    const int nwaves = gridDim.x * 4;

    double wreg[4][8];
#pragma unroll
    for (int i = 0; i < 4; ++i)
#pragma unroll
        for (int j = 0; j < 8; ++j)
            wreg[i][j] = Wlr[(lane * 4 + i) * 8 + j];

    for (int row = wid; row < N_SRC; row += nwaves) {
        float4 xv = *((const float4*)(x + (size_t)row * IN_F + lane * 4));
        double acc[8];
#pragma unroll
        for (int j = 0; j < 8; ++j) acc[j] = 0.0;
        const double xd[4] = {(double)xv.x, (double)xv.y, (double)xv.z, (double)xv.w};
#pragma unroll
        for (int i = 0; i < 4; ++i)
#pragma unroll
            for (int j = 0; j < 8; ++j)
                acc[j] += xd[i] * wreg[i][j];
#pragma unroll
        for (int j = 0; j < 8; ++j) {
#pragma unroll
            for (int m = 32; m >= 1; m >>= 1)
                acc[j] += __shfl_xor(acc[j], m);
        }
        if (lane == 0) {
#pragma unroll
            for (int hh = 0; hh < 4; ++hh) {
                el[(size_t)row * NH + hh] = acc[hh];
                er_src[(size_t)row * NH + hh] = acc[4 + hh];
            }
        }
    }
}

// ---------------- K3: gather er for dst nodes ----------------
__global__ __launch_bounds__(256) void k_gather(const int* __restrict__ dst_to_src,
                                                const double* __restrict__ er_src,
                                                double* __restrict__ er_dst) {
    int gid = blockIdx.x * 256 + threadIdx.x;
    if (gid >= N_DST * NH) return;
    int nd = gid >> 2, hh = gid & 3;
    er_dst[gid] = er_src[(size_t)dst_to_src[nd] * NH + hh];
}

// ---------------- CSR build ----------------
__global__ __launch_bounds__(256) void k_hist(const int* __restrict__ dst_idx,
                                              int* __restrict__ cnt) {
    int gid = blockIdx.x * 256 + threadIdx.x;
    if (gid >= NE) return;
    atomicAdd(cnt + dst_idx[gid], 1);
}

__global__ __launch_bounds__(256) void k_scan(const int* __restrict__ cnt,
                                              int* __restrict__ offsets) {
    __shared__ int wsum[4];
    __shared__ int carry;
    int tid = threadIdx.x, lane = tid & 63, w = tid >> 6;
    if (tid == 0) carry = 0;
    __syncthreads();
    for (int base = 0; base < N_DST; base += 256) {
        int i = base + tid;
        int v = (i < N_DST) ? cnt[i] : 0;
        int s = v;
#pragma unroll
        for (int off = 1; off < 64; off <<= 1) {
            int t = __shfl_up(s, off);
            if (lane >= off) s += t;
        }
        if (lane == 63) wsum[w] = s;
        __syncthreads();
        int wprefix = 0;
        for (int k = 0; k < w; ++k) wprefix += wsum[k];
        int incl = s + wprefix + carry;
        if (i < N_DST) offsets[i + 1] = incl;
        __syncthreads();
        if (tid == 255) carry = incl;
        __syncthreads();
    }
    if (tid == 0) offsets[0] = 0;
}

__global__ __launch_bounds__(256) void k_fill(const int* __restrict__ src_idx,
                                              const int* __restrict__ dst_idx,
                                              const int* __restrict__ offsets,
                                              int* __restrict__ cursor,
                                              int* __restrict__ edge_src) {
    int gid = blockIdx.x * 256 + threadIdx.x;
    if (gid >= NE) return;
    int d = dst_idx[gid];
    int pos = offsets[d] + atomicAdd(cursor + d, 1);
    edge_src[pos] = src_idx[gid];
}

// ---------------- K5: fused segment-softmax-normalize + weighted gather ----------------
// one block (128 threads) per dst node
__global__ __launch_bounds__(128) void k_fused(const int* __restrict__ offsets,
                                               const int* __restrict__ edge_src,
                                               const double* __restrict__ el,
                                               const double* __restrict__ er_dst,
                                               const float* __restrict__ h,
                                               float* __restrict__ out) {
    const int d = blockIdx.x;
    const int tid = threadIdx.x;
    const int beg = offsets[d], end = offsets[d + 1];
    const int deg = end - beg;

    __shared__ double red[128][NH];   // 4 KB
    __shared__ double S_sh[NH];
    __shared__ double att_sh[32][NH]; // 1 KB
    __shared__ int s_sh[32];

    double er4[NH];
#pragma unroll
    for (int hh = 0; hh < NH; ++hh) er4[hh] = er_dst[(size_t)d * NH + hh];

    // phase 1: S[h] = sum over edges of leaky(el[s][h] + er[d][h])
    double sum4[NH] = {0.0, 0.0, 0.0, 0.0};
    for (int j = tid; j < deg; j += 128) {
        int s = edge_src[beg + j];
#pragma unroll
        for (int hh = 0; hh < NH; ++hh) {
            double e = el[(size_t)s * NH + hh] + er4[hh];
            e = (e >= 0.0) ? e : 0.2 * e;
            sum4[hh] += e;
        }
    }
#pragma unroll
    for (int hh = 0; hh < NH; ++hh) red[tid][hh] = sum4[hh];
    __syncthreads();
    for (int off = 64; off >= 1; off >>= 1) {
        if (tid < off) {
#pragma unroll
            for (int hh = 0; hh < NH; ++hh) red[tid][hh] += red[tid + off][hh];
        }
        __syncthreads();
    }
    if (tid < NH) S_sh[tid] = red[0][tid];
    __syncthreads();

    // phase 2: out[d][c] = sum over edges of (e/S) * h[s][c]
    const int c = tid;
    const int hc = c >> 5;
    double acc = 0.0;
    for (int base = 0; base < deg; base += 32) {
        int nchunk = min(32, deg - base);
        int j = tid >> 2, hh = tid & 3;
        if (j < nchunk) {
            int s = edge_src[beg + base + j];
            if (hh == 0) s_sh[j] = s;
            double e = el[(size_t)s * NH + hh] + er4[hh];
            e = (e >= 0.0) ? e : 0.2 * e;
            att_sh[j][hh] = e / S_sh[hh];
        }
        __syncthreads();
        for (int jj = 0; jj < nchunk; ++jj) {
            acc += att_sh[jj][hc] * (double)h[(size_t)s_sh[jj] * NCOL + c];
        }
        __syncthreads();
    }
    out[(size_t)d * NCOL + c] = (float)acc;
}

extern "C" void kernel_launch(void* const* d_in, const int* in_sizes, int n_in,
                              void* d_out, int out_size, void* d_ws, size_t ws_size,
                              hipStream_t stream) {
    const float* x      = (const float*)d_in[0];
    const float* W      = (const float*)d_in[1];
    const float* attn_l = (const float*)d_in[2];
    const float* attn_r = (const float*)d_in[3];
    const int* src_idx  = (const int*)d_in[4];
    const int* dst_idx  = (const int*)d_in[5];
    const int* dst_to_src = (const int*)d_in[6];
    float* out = (float*)d_out;

    char* p = (char*)d_ws;
    double* Wlr    = (double*)p;  p += (size_t)IN_F * 8 * sizeof(double);
    double* el     = (double*)p;  p += (size_t)N_SRC * NH * sizeof(double);
    double* er_src = (double*)p;  p += (size_t)N_SRC * NH * sizeof(double);
    double* er_dst = (double*)p;  p += (size_t)N_DST * NH * sizeof(double);
    float*  h      = (float*)p;   p += (size_t)N_SRC * NCOL * sizeof(float);
    int*    cnt     = (int*)p;    p += (size_t)N_DST * sizeof(int);
    int*    offsets = (int*)p;    p += (size_t)(N_DST + 1) * sizeof(int);
    int*    cursor  = (int*)p;    p += (size_t)N_DST * sizeof(int);
    int*    edge_src = (int*)p;   p += (size_t)NE * sizeof(int);

    hipMemsetAsync(cnt, 0, (size_t)N_DST * sizeof(int), stream);
    hipMemsetAsync(cursor, 0, (size_t)N_DST * sizeof(int), stream);

    k_prep<<<1, IN_F, 0, stream>>>(W, attn_l, attn_r, Wlr);
    k_gemm<<<(N_SRC + 63) / 64, 256, 0, stream>>>(x, W, h);
    k_scores<<<512, 256, 0, stream>>>(x, Wlr, el, er_src);
    k_gather<<<(N_DST * NH + 255) / 256, 256, 0, stream>>>(dst_to_src, er_src, er_dst);
    k_hist<<<(NE + 255) / 256, 256, 0, stream>>>(dst_idx, cnt);
    k_scan<<<1, 256, 0, stream>>>(cnt, offsets);
    k_fill<<<(NE + 255) / 256, 256, 0, stream>>>(src_idx, dst_idx, offsets, cursor, edge_src);
    k_fused<<<N_DST, 128, 0, stream>>>(offsets, edge_src, el, er_dst, h, out);
}